// Round 20
// baseline (287.685 us; speedup 1.0000x reference)
//
#include <hip/hip_runtime.h>
#include <stdint.h>
#include <stddef.h>

// ---------- types ----------
typedef _Float16 half_t;
typedef half_t half8  __attribute__((ext_vector_type(8)));
typedef half_t half4v __attribute__((ext_vector_type(4)));
typedef float  f32x4  __attribute__((ext_vector_type(4)));

__device__ __forceinline__ float fast_sigmoid(float x) {
    float e = __builtin_amdgcn_exp2f(-1.44269504f * x);
    return __builtin_amdgcn_rcpf(1.0f + e);
}
__device__ __forceinline__ float fast_tanh(float x) {
    float e = __builtin_amdgcn_exp2f(2.88539008f * x);
    return 1.0f - 2.0f * __builtin_amdgcn_rcpf(1.0f + e);
}

// ---------------------------------------------------------------------------
// Prep: W [1024][256] f32 row-major -> wave-window-contiguous MFMA-B order
// for the 4-wave / 32-row geometry. Tile T = g*16 + w*4 + j (gate g, wave w,
// sub-tile j in [0,4)); slot v = g*4 + j in [0,16). Element addr:
//   (((w*8 + kt)*16 + v)*64 + l)*8 + e
// so window (kt,h) for wave w is a contiguous 4 KB run per half h (v in
// [h*8, h*8+8)). Value: B[k = kt*32 + (l>>4)*8 + e, col = T*16 + (l&15)] --
// same (lane-group,elem)->k bijection as the LDS A-fragments (validated
// R1-R19, absmax 2e-3).
// ---------------------------------------------------------------------------
__global__ __launch_bounds__(64) void shuffle_w_kernel(
    const float* __restrict__ W, half_t* __restrict__ out)
{
    const int blk = blockIdx.x;         // 512 = 64 T * 8 kt
    const int T = blk >> 3, kt = blk & 7;
    const int l = threadIdx.x;
    const int g = T >> 4, wj = T & 15, w = wj >> 2, j = wj & 3;
    const int v = g * 4 + j;
    const int col = T * 16 + (l & 15);
    const int k0 = kt * 32 + ((l >> 4) << 3);
    half8 vv;
#pragma unroll
    for (int e = 0; e < 8; ++e) vv[e] = (half_t)W[col * 256 + k0 + e];
    *reinterpret_cast<half8*>(
        out + (((size_t)(w * 8 + kt) * 16 + v) * 64 + l) * 8) = vv;
}

// ---------------------------------------------------------------------------
// SINGLE-PASS 4-gate GEMM, M=32 (2 mt), 16 N-tiles/wave. kt windows PINNED
// (unroll 1 + sched_barrier); each kt body has TWO compile-time halves
// (h = 0: gates i,f; h = 1: gates g,o) so all acc indices are static
// (rule #20). Per half: 8 contiguous b-frags (1 base), 2 a-frags (shared
// across halves), 16 MFMA, cowork in the shadow.
// In-flight arch: b 32 + a 8 + bases ~8 (acc in AGPR).
// ---------------------------------------------------------------------------
template <typename CoWork>
__device__ __forceinline__ void gemm_all(
    f32x4* acc, const half_t* __restrict__ lhx,
    const half_t* Ws, int w, int lm, int lg, int l, CoWork&& cowork)
{
    asm volatile("" : "+v"(Ws));   // anti-LICM: recompute bases per call
    const half_t* wb = Ws + (size_t)w * 65536 + l * 8;
#pragma unroll 1
    for (int kt = 0; kt < 8; ++kt) {
        const half_t* q = wb + kt * 8192;
        half8 a[2];
#pragma unroll
        for (int mt = 0; mt < 2; ++mt) {
            const int p = mt * 16 + lm;
            const int k = (kt * 32 + lg * 8) ^ ((p & 7) << 4);
            a[mt] = *reinterpret_cast<const half8*>(&lhx[p * 256 + k]);
        }
        {   // ---- half 0: v = 0..7 (gates i, f) ----
            half8 b[8];
#pragma unroll
            for (int vv = 0; vv < 8; ++vv)
                b[vv] = *reinterpret_cast<const half8*>(q + vv * 512);
#pragma unroll
            for (int vv = 0; vv < 8; ++vv)
#pragma unroll
                for (int mt = 0; mt < 2; ++mt)
                    acc[mt * 16 + vv] = __builtin_amdgcn_mfma_f32_16x16x32_f16(
                        a[mt], b[vv], acc[mt * 16 + vv], 0, 0, 0);
            cowork(kt * 2);
            __builtin_amdgcn_sched_barrier(0);
        }
        {   // ---- half 1: v = 8..15 (gates g, o) ----
            half8 b[8];
#pragma unroll
            for (int vv = 0; vv < 8; ++vv)
                b[vv] = *reinterpret_cast<const half8*>(q + 4096 + vv * 512);
#pragma unroll
            for (int vv = 0; vv < 8; ++vv)
#pragma unroll
                for (int mt = 0; mt < 2; ++mt)
                    acc[mt * 16 + 8 + vv] = __builtin_amdgcn_mfma_f32_16x16x32_f16(
                        a[mt], b[vv], acc[mt * 16 + 8 + vv], 0, 0, 0);
            cowork(kt * 2 + 1);
            __builtin_amdgcn_sched_barrier(0);
        }
    }
}

// ---------------------------------------------------------------------------
// Persistent LSTM: block = 32 rows x 16 steps, 4 waves (256 threads),
// LDS = hx 16 KB + xp 64 KB = 80 KB -> TWO independent blocks per CU at the
// SAME 2-waves/SIMD register budget (R12-R19's). R18 post-mortem: single
// block is barrier-lockstepped (epilogue VALU with MFMA idle, gemm with
// VALU idle); two blocks with independent barriers phase-offset and fill
// each other's pipes. R13's failure causes individually fixed: R18-style
// single-window b (no 64-reg dbuf), chunked init, anti-LICM, static acc
// indices. Ledger: cxr 32 + b 32 + a 8 + head 8 + addr ~15 = ~95 <= 128.
// ---------------------------------------------------------------------------
__global__ __launch_bounds__(256, 2)
void lstm_kernel(
    const float* __restrict__ x,      // [8][256][1600]
    const float* __restrict__ hx0,    // [12800][256]
    const float* __restrict__ cx0,    // [12800][256]
    const float* __restrict__ b_ih,   // [1024]
    const float* __restrict__ b_hh,   // [1024]
    const float* __restrict__ W_lin,  // [2][256]
    const float* __restrict__ b_lin,  // [2]
    const half_t* __restrict__ Wih_s, // shuffled f16
    const half_t* __restrict__ Whh_s, // shuffled f16
    float* __restrict__ out)          // [12800][16][2]
{
    __shared__ __align__(16) half_t lds_hx[32 * 256];        // 16 KB
    __shared__ __align__(16) half_t lds_xp[4 * 32 * 64 * 4]; // 64 KB

    const int tid = threadIdx.x;
    const int w  = tid >> 6;   // wave 0..3 owns h-cols [w*64, w*64+64)
    const int l  = tid & 63;
    const int lm = l & 15;
    const int lg = l >> 4;

    const int row0 = blockIdx.x * 32;     // 400 blocks * 32 rows
    const int bb_  = row0 / 1600;         // 32 | 1600: no batch crossing
    const int p0   = row0 % 1600;

    // ---- stage x tile into lds_hx, f16 swizzled (coalesced on p) ----
    {
        const float* xin = x + (size_t)bb_ * 409600 + p0;   // x[b][c][p0+p]
        for (int it = 0; it < 32; ++it) {
            int idx = it * 256 + tid;
            int p = idx & 31, c = idx >> 5;
            lds_hx[p * 256 + (c ^ ((p & 7) << 4))] = (half_t)xin[c * 1600 + p];
        }
    }
    __syncthreads();

    f32x4 acc[32];
    auto nocw = [](int) {};

    // ---------------- phase 0: x_proj = x @ W_ih^T + b_ih + b_hh ----------
#pragma unroll
    for (int g = 0; g < 4; ++g)
#pragma unroll
        for (int j = 0; j < 4; ++j) {
            int col = (g * 16 + w * 4 + j) * 16 + lm;
            float bias = b_ih[col] + b_hh[col];
#pragma unroll
            for (int mt = 0; mt < 2; ++mt)
                acc[mt * 16 + g * 4 + j] = (f32x4){bias, bias, bias, bias};
        }
    gemm_all(acc, lds_hx, Wih_s, w, lm, lg, l, nocw);

    // dump x_proj to own-wave LDS region as f16 (read back identically)
#pragma unroll
    for (int f = 0; f < 32; ++f) {
        half4v xv;
#pragma unroll
        for (int r = 0; r < 4; ++r) xv[r] = (half_t)acc[f][r];
        *reinterpret_cast<half4v*>(&lds_xp[((w * 32 + f) * 64 + l) * 4]) = xv;
    }
    __syncthreads();   // x tile fully consumed, xp written

    // ---- stage h0 into lds_hx (coalesced on c); cx into registers ----
    {
        const float* hin = hx0 + (size_t)row0 * 256;
        for (int it = 0; it < 32; ++it) {
            int idx = it * 256 + tid;
            int c = idx & 255, p = idx >> 8;
            lds_hx[p * 256 + (c ^ ((p & 7) << 4))] = (half_t)hin[p * 256 + c];
        }
    }
    float cxr[32];
#pragma unroll
    for (int mt = 0; mt < 2; ++mt)
#pragma unroll
        for (int j = 0; j < 4; ++j)
#pragma unroll
            for (int r = 0; r < 4; ++r) {
                int p = mt * 16 + lg * 4 + r;
                int c = w * 64 + j * 16 + lm;
                cxr[(mt * 4 + j) * 4 + r] = cx0[(size_t)(row0 + p) * 256 + c];
            }
    const float blin0 = b_lin[0], blin1 = b_lin[1];
    const int ph = tid >> 3;          // head: row 0..31
    const int ho = (tid >> 2) & 1;    // head: output 0..1
    const int hq = tid & 3;           // head: quarter of 256 h-cols
    __syncthreads();

    // ---------------- 16 recurrent steps ----------------
#pragma unroll 1
    for (int t = 0; t < 16; ++t) {
        // head(t-1): 1 chunk per window (16 windows x 4 cols = 64 cols/thr);
        // W_lin float4 pipelined one window ahead (8-reg state)
        const float* wl = W_lin + ho * 256 + hq * 64;
        asm volatile("" : "+v"(wl));
        float hs = 0.0f;
        float4 hwv;
        if (t > 0) hwv = *reinterpret_cast<const float4*>(wl);
        auto head_cw = [&](int wi) {
            if (t > 0) {
                int c0 = hq * 64 + wi * 4;
                half4v u = *reinterpret_cast<const half4v*>(
                    &lds_hx[ph * 256 + (c0 ^ ((ph & 7) << 4))]);
                float4 wv = hwv;
                if (wi < 15)
                    hwv = *reinterpret_cast<const float4*>(wl + (wi + 1) * 4);
                float h0 = (float)u[0], h1 = (float)u[1];
                float h2 = (float)u[2], h3 = (float)u[3];
                hs += fmaxf(h0, 0.01f * h0) * wv.x;
                hs += fmaxf(h1, 0.01f * h1) * wv.y;
                hs += fmaxf(h2, 0.01f * h2) * wv.z;
                hs += fmaxf(h3, 0.01f * h3) * wv.w;
            }
        };

        // acc init = x_proj, CHUNKED 4-frags-per-fence (R14/R18-proven)
#pragma unroll
        for (int fc = 0; fc < 32; fc += 4) {
#pragma unroll
            for (int f = fc; f < fc + 4; ++f) {
                half4v u = *reinterpret_cast<const half4v*>(
                    &lds_xp[((w * 32 + f) * 64 + l) * 4]);
#pragma unroll
                for (int r = 0; r < 4; ++r) acc[f][r] = (float)u[r];
            }
            __builtin_amdgcn_sched_barrier(0);
        }

        // single GEMM pass: all 4 gates; head(t-1) in the MFMA shadow
        gemm_all(acc, lds_hx, Whh_s, w, lm, lg, l, head_cw);
        if (t > 0) {
            hs += __shfl_xor(hs, 1);
            hs += __shfl_xor(hs, 2);
            if (hq == 0)
                out[((size_t)(row0 + ph) * 16 + (t - 1)) * 2 + ho] =
                    hs + (ho ? blin1 : blin0);
        }

        __syncthreads();   // all waves finished reading lds_hx(t)

        // epilogue: cell update (all 4 gates local); write hx(t+1)
#pragma unroll
        for (int mt = 0; mt < 2; ++mt)
#pragma unroll
            for (int j = 0; j < 4; ++j)
#pragma unroll
                for (int r = 0; r < 4; ++r) {
                    const int ci = (mt * 4 + j) * 4 + r;
                    float iv = acc[mt * 16 + 0 + j][r];
                    float fv = acc[mt * 16 + 4 + j][r];
                    float gv = acc[mt * 16 + 8 + j][r];
                    float ov = acc[mt * 16 + 12 + j][r];
                    float cxn = fast_sigmoid(fv) * cxr[ci] +
                                fast_sigmoid(iv) * fast_tanh(gv);
                    cxr[ci] = cxn;
                    float h = fast_sigmoid(ov) * fast_tanh(cxn);
                    int p  = mt * 16 + lg * 4 + r;
                    int cc = w * 64 + j * 16 + lm;
                    lds_hx[p * 256 + (cc ^ ((p & 7) << 4))] = (half_t)h;
                }
        __syncthreads();   // hx(t+1) visible to all (next gemm + head)
    }

    // ---- final head (t = 15) ----
    {
        const float* wl = W_lin + ho * 256 + hq * 64;
        asm volatile("" : "+v"(wl));
        float s = 0.0f;
#pragma unroll 2
        for (int cb = 0; cb < 16; ++cb) {
            int c0 = hq * 64 + cb * 4;
            half4v u = *reinterpret_cast<const half4v*>(
                &lds_hx[ph * 256 + (c0 ^ ((ph & 7) << 4))]);
            float4 wv = *reinterpret_cast<const float4*>(wl + cb * 4);
            float h0 = (float)u[0], h1 = (float)u[1];
            float h2 = (float)u[2], h3 = (float)u[3];
            s += fmaxf(h0, 0.01f * h0) * wv.x;
            s += fmaxf(h1, 0.01f * h1) * wv.y;
            s += fmaxf(h2, 0.01f * h2) * wv.z;
            s += fmaxf(h3, 0.01f * h3) * wv.w;
        }
        s += __shfl_xor(s, 1);
        s += __shfl_xor(s, 2);
        if (hq == 0)
            out[((size_t)(row0 + ph) * 16 + 15) * 2 + ho] =
                s + (ho ? blin1 : blin0);
    }
}

// ---------------------------------------------------------------------------
extern "C" void kernel_launch(void* const* d_in, const int* in_sizes, int n_in,
                              void* d_out, int out_size, void* d_ws, size_t ws_size,
                              hipStream_t stream)
{
    const float* x    = (const float*)d_in[0];
    const float* hx   = (const float*)d_in[1];
    const float* cx   = (const float*)d_in[2];
    const float* Wih  = (const float*)d_in[3];
    const float* Whh  = (const float*)d_in[4];
    const float* bih  = (const float*)d_in[5];
    const float* bhh  = (const float*)d_in[6];
    const float* Wlin = (const float*)d_in[7];
    const float* blin = (const float*)d_in[8];
    float* out = (float*)d_out;

    half_t* wih_s = (half_t*)d_ws;             // 512 KB
    half_t* whh_s = wih_s + 1024 * 256;        // 512 KB

    shuffle_w_kernel<<<512, 64, 0, stream>>>(Wih, wih_s);
    shuffle_w_kernel<<<512, 64, 0, stream>>>(Whh, whh_s);
    lstm_kernel<<<400, 256, 0, stream>>>(x, hx, cx, bih, bhh, Wlin, blin,
                                         wih_s, whh_s, out);
}

// Round 21
// 249.249 us; speedup vs baseline: 1.1542x; 1.1542x over previous
//
#include <hip/hip_runtime.h>
#include <stdint.h>
#include <stddef.h>

// ---------- types ----------
typedef _Float16 half_t;
typedef half_t half8  __attribute__((ext_vector_type(8)));
typedef half_t half4v __attribute__((ext_vector_type(4)));
typedef float  f32x4  __attribute__((ext_vector_type(4)));

// ---------------------------------------------------------------------------
// Prep: W [1024][256] f32 row-major -> wave-window-contiguous MFMA-B order.
// Tile T = g*16 + w*2 + j; slot v = g*2 + j. Element addr:
// (((w*8 + kt)*8 + v)*64 + l)*8 + e  -- the 8 fragments a wave needs in
// window kt are one contiguous 8 KB run. Value: B[k = kt*32 + (l>>4)*8 + e,
// col = T*16 + (l&15)] -- same bijection as the LDS A-fragments
// (validated R1-R20, absmax 2e-3).
// ---------------------------------------------------------------------------
__global__ __launch_bounds__(64) void shuffle_w_kernel(
    const float* __restrict__ W, half_t* __restrict__ out)
{
    const int blk = blockIdx.x;         // 512 = 64 T * 8 kt
    const int T = blk >> 3, kt = blk & 7;
    const int l = threadIdx.x;
    const int w = (T & 15) >> 1, j = T & 1, g = T >> 4;
    const int v = g * 2 + j;
    const int col = T * 16 + (l & 15);
    const int k0 = kt * 32 + ((l >> 4) << 3);
    half8 vv;
#pragma unroll
    for (int e = 0; e < 8; ++e) vv[e] = (half_t)W[col * 256 + k0 + e];
    *reinterpret_cast<half8*>(
        out + ((size_t)((w * 8 + kt) * 8 + v) * 64 + l) * 8) = vv;
}

// ---------------------------------------------------------------------------
// Quad-batched reciprocal: 4x 1/d with ONE v_rcp + 10 muls (exact product
// prefix/suffix trick). Trans ~16 cyc vs VALU 2 cyc -> saves ~42 cyc per
// quad on the shared trans unit. R21's lever: epilogue rcp count 160->40.
// ---------------------------------------------------------------------------
__device__ __forceinline__ void qrcp4(
    float d0, float d1, float d2, float d3,
    float& r0, float& r1, float& r2, float& r3)
{
    float p01  = d0 * d1;
    float p012 = p01 * d2;
    float p    = p012 * d3;
    float R    = __builtin_amdgcn_rcpf(p);
    float s2   = d2 * d3;
    float s1   = d1 * s2;
    r0 = R * s1;
    r1 = (R * s2) * d0;
    r2 = (R * p01) * d3;
    r3 = R * p012;
}

// ---------------------------------------------------------------------------
// SINGLE-PASS 4-gate GEMM (R18-validated, 239 us): acc[mt*8+v] += hx @ W^T.
// kt windows PINNED (unroll 1 + sched_barrier). Per window: 8 contiguous
// b-frags (2 bases, imm offsets), 4 a-frags, 32 MFMA, cowork in the shadow.
// ---------------------------------------------------------------------------
template <typename CoWork>
__device__ __forceinline__ void gemm_all(
    f32x4* acc, const half_t* __restrict__ lhx,
    const half_t* Ws, int w, int lm, int lg, int l, CoWork&& cowork)
{
    asm volatile("" : "+v"(Ws));   // anti-LICM: recompute bases per call
    const half_t* wb = Ws + (size_t)w * 32768 + l * 8;
#pragma unroll 1
    for (int kt = 0; kt < 8; ++kt) {
        const half_t* q0 = wb + kt * 4096;
        const half_t* q1 = q0 + 2048;
        half8 b[8];
#pragma unroll
        for (int v = 0; v < 4; ++v) {
            b[v]     = *reinterpret_cast<const half8*>(q0 + v * 512);
            b[4 + v] = *reinterpret_cast<const half8*>(q1 + v * 512);
        }
        half8 a[4];
#pragma unroll
        for (int mt = 0; mt < 4; ++mt) {
            const int p = mt * 16 + lm;
            const int k = (kt * 32 + lg * 8) ^ ((p & 7) << 4);
            a[mt] = *reinterpret_cast<const half8*>(&lhx[p * 256 + k]);
        }
#pragma unroll
        for (int v = 0; v < 8; ++v)
#pragma unroll
            for (int mt = 0; mt < 4; ++mt)
                acc[mt * 8 + v] = __builtin_amdgcn_mfma_f32_16x16x32_f16(
                    a[mt], b[v], acc[mt * 8 + v], 0, 0, 0);
        cowork(kt);               // VALU work in the MFMA shadow
        __builtin_amdgcn_sched_barrier(0);   // window boundary (anti-hoist)
    }
}

// ---------------------------------------------------------------------------
// Persistent LSTM: block = 64 rows x 16 steps, 8 waves (512 threads),
// 1 blk/CU, 2 waves/SIMD. R18 base (239 us, ZERO spills; R19 merged-init
// and R20 two-block variants both regressed and are reverted).
// R21: epilogue transcendental batching -- all 5 activations are 1/(1+e)
// forms; the (mt,j) group's 4 cells share ONE v_rcp per function via qrcp4
// (rcp count 160->40/thread/step; trans unit is ~10K cyc/SIMD/step, on par
// with the whole MFMA region). Only tanh(c)'s exp arg needs a +-10 clamp
// (c can reach +-16; sigmoid/tanh(g) args are bounded ~+-8).
// Per-group sched_barrier keeps quad transients (~50 regs) from merging.
// LDS: hx 32 KB (XOR-swizzled) + xp 128 KB = 160 KB.
// ---------------------------------------------------------------------------
__global__ __launch_bounds__(512)
void lstm_kernel(
    const float* __restrict__ x,      // [8][256][1600]
    const float* __restrict__ hx0,    // [12800][256]
    const float* __restrict__ cx0,    // [12800][256]
    const float* __restrict__ b_ih,   // [1024]
    const float* __restrict__ b_hh,   // [1024]
    const float* __restrict__ W_lin,  // [2][256]
    const float* __restrict__ b_lin,  // [2]
    const half_t* __restrict__ Wih_s, // shuffled f16
    const half_t* __restrict__ Whh_s, // shuffled f16
    float* __restrict__ out)          // [12800][16][2]
{
    __shared__ __align__(16) half_t lds_hx[64 * 256];        // 32 KB
    __shared__ __align__(16) half_t lds_xp[8 * 32 * 64 * 4]; // 128 KB

    const int tid = threadIdx.x;
    const int w  = tid >> 6;   // wave 0..7 owns h-cols [w*32, w*32+32)
    const int l  = tid & 63;
    const int lm = l & 15;
    const int lg = l >> 4;
    const int w2 = w * 2;

    const int row0 = blockIdx.x * 64;     // 200 blocks * 64 rows
    const int bb_  = row0 / 1600;
    const int p0   = row0 % 1600;

    // ---- stage x tile into lds_hx, f16 swizzled (coalesced on p) ----
    {
        const float* xin = x + (size_t)bb_ * 409600 + p0;   // x[b][c][p0+p]
        for (int it = 0; it < 32; ++it) {
            int idx = it * 512 + tid;
            int p = idx & 63, c = idx >> 6;
            lds_hx[p * 256 + (c ^ ((p & 7) << 4))] = (half_t)xin[c * 1600 + p];
        }
    }
    __syncthreads();

    f32x4 acc[32];
    auto nocw = [](int) {};

    // ---------------- phase 0: x_proj = x @ W_ih^T + b_ih + b_hh ----------
#pragma unroll
    for (int g = 0; g < 4; ++g)
#pragma unroll
        for (int j = 0; j < 2; ++j) {
            int col = (g * 16 + w2 + j) * 16 + lm;
            float bias = b_ih[col] + b_hh[col];
#pragma unroll
            for (int mt = 0; mt < 4; ++mt)
                acc[mt * 8 + g * 2 + j] = (f32x4){bias, bias, bias, bias};
        }
    gemm_all(acc, lds_hx, Wih_s, w, lm, lg, l, nocw);

    // dump x_proj to own-wave LDS region as f16 (read back identically)
#pragma unroll
    for (int f = 0; f < 32; ++f) {
        half4v xv;
#pragma unroll
        for (int r = 0; r < 4; ++r) xv[r] = (half_t)acc[f][r];
        *reinterpret_cast<half4v*>(&lds_xp[((w * 32 + f) * 64 + l) * 4]) = xv;
    }
    __syncthreads();   // x tile fully consumed, xp written

    // ---- stage h0 into lds_hx (coalesced on c); cx into registers ----
    {
        const float* hin = hx0 + (size_t)row0 * 256;
        for (int it = 0; it < 32; ++it) {
            int idx = it * 512 + tid;
            int c = idx & 255, p = idx >> 8;
            lds_hx[p * 256 + (c ^ ((p & 7) << 4))] = (half_t)hin[p * 256 + c];
        }
    }
    float cxr[32];
#pragma unroll
    for (int mt = 0; mt < 4; ++mt)
#pragma unroll
        for (int j = 0; j < 2; ++j)
#pragma unroll
            for (int r = 0; r < 4; ++r) {
                int p = mt * 16 + lg * 4 + r;
                int c = w * 32 + j * 16 + lm;
                cxr[(mt * 2 + j) * 4 + r] = cx0[(size_t)(row0 + p) * 256 + c];
            }
    const float blin0 = b_lin[0], blin1 = b_lin[1];
    const int ph = tid >> 3;          // head: row 0..63
    const int ho = (tid >> 2) & 1;    // head: output 0..1
    const int hq = tid & 3;           // head: quarter of 256 h-cols
    __syncthreads();

    // ---------------- 16 recurrent steps ----------------
#pragma unroll 1
    for (int t = 0; t < 16; ++t) {
        // head(t-1) state: W_lin float4s pipelined one window ahead (R16)
        const float* wl = W_lin + ho * 256 + hq * 64;
        asm volatile("" : "+v"(wl));
        float hs = 0.0f;
        float4 hwv0, hwv1;
        if (t > 0) {
            hwv0 = *reinterpret_cast<const float4*>(wl + 0);
            hwv1 = *reinterpret_cast<const float4*>(wl + 4);
        }
        auto head_cw = [&](int wi) {
            if (t > 0) {
#pragma unroll
                for (int ii = 0; ii < 2; ++ii) {
                    int cb = wi * 2 + ii;
                    int c0 = hq * 64 + cb * 4;
                    half4v u = *reinterpret_cast<const half4v*>(
                        &lds_hx[ph * 256 + (c0 ^ ((ph & 7) << 4))]);
                    float4 wv = ii ? hwv1 : hwv0;
                    if (cb + 2 < 16) {   // prefetch next window's float4
                        float4 nx = *reinterpret_cast<const float4*>(
                            wl + (cb + 2) * 4);
                        if (ii) hwv1 = nx; else hwv0 = nx;
                    }
                    float h0 = (float)u[0], h1 = (float)u[1];
                    float h2 = (float)u[2], h3 = (float)u[3];
                    hs += fmaxf(h0, 0.01f * h0) * wv.x;
                    hs += fmaxf(h1, 0.01f * h1) * wv.y;
                    hs += fmaxf(h2, 0.01f * h2) * wv.z;
                    hs += fmaxf(h3, 0.01f * h3) * wv.w;
                }
            }
        };

        // acc init = x_proj, CHUNKED 4-frags-per-fence (R14/R18-proven)
#pragma unroll
        for (int fc = 0; fc < 32; fc += 4) {
#pragma unroll
            for (int f = fc; f < fc + 4; ++f) {
                half4v u = *reinterpret_cast<const half4v*>(
                    &lds_xp[((w * 32 + f) * 64 + l) * 4]);
#pragma unroll
                for (int r = 0; r < 4; ++r) acc[f][r] = (float)u[r];
            }
            __builtin_amdgcn_sched_barrier(0);
        }

        // single GEMM pass: all 4 gates; head(t-1) in the MFMA shadow
        gemm_all(acc, lds_hx, Whh_s, w, lm, lg, l, head_cw);
        if (t > 0) {
            hs += __shfl_xor(hs, 1);
            hs += __shfl_xor(hs, 2);
            if (hq == 0)
                out[((size_t)(row0 + ph) * 16 + (t - 1)) * 2 + ho] =
                    hs + (ho ? blin1 : blin0);
        }

        __syncthreads();   // all waves finished reading lds_hx(t)

        // epilogue: cell update with quad-batched reciprocals.
        // sig(x) = 1/(1+exp2(-1.4427x)); tanh(x) = 1 - 2/(1+exp2(2.8854x)).
#pragma unroll
        for (int mt = 0; mt < 4; ++mt)
#pragma unroll
            for (int j = 0; j < 2; ++j) {
                float di[4], df[4], dg[4], dv[4];
#pragma unroll
                for (int r = 0; r < 4; ++r) {
                    di[r] = 1.0f + __builtin_amdgcn_exp2f(
                        -1.44269504f * acc[mt * 8 + 0 + j][r]);
                    df[r] = 1.0f + __builtin_amdgcn_exp2f(
                        -1.44269504f * acc[mt * 8 + 2 + j][r]);
                    dg[r] = 1.0f + __builtin_amdgcn_exp2f(
                        2.88539008f * acc[mt * 8 + 4 + j][r]);
                    dv[r] = 1.0f + __builtin_amdgcn_exp2f(
                        -1.44269504f * acc[mt * 8 + 6 + j][r]);
                }
                float ri[4], rf[4], rg[4], ro[4];
                qrcp4(di[0], di[1], di[2], di[3], ri[0], ri[1], ri[2], ri[3]);
                qrcp4(df[0], df[1], df[2], df[3], rf[0], rf[1], rf[2], rf[3]);
                qrcp4(dg[0], dg[1], dg[2], dg[3], rg[0], rg[1], rg[2], rg[3]);
                qrcp4(dv[0], dv[1], dv[2], dv[3], ro[0], ro[1], ro[2], ro[3]);
                float dc[4];
#pragma unroll
                for (int r = 0; r < 4; ++r) {
                    const int ci = (mt * 2 + j) * 4 + r;
                    float tg  = 1.0f - 2.0f * rg[r];
                    float cxn = rf[r] * cxr[ci] + ri[r] * tg;
                    cxr[ci] = cxn;
                    float cc = fminf(fmaxf(cxn, -10.0f), 10.0f);  // overflow guard
                    dc[r] = 1.0f + __builtin_amdgcn_exp2f(2.88539008f * cc);
                }
                float rc[4];
                qrcp4(dc[0], dc[1], dc[2], dc[3], rc[0], rc[1], rc[2], rc[3]);
#pragma unroll
                for (int r = 0; r < 4; ++r) {
                    float h = ro[r] * (1.0f - 2.0f * rc[r]);
                    int p  = mt * 16 + lg * 4 + r;
                    int cc = w * 32 + j * 16 + lm;
                    lds_hx[p * 256 + (cc ^ ((p & 7) << 4))] = (half_t)h;
                }
                __builtin_amdgcn_sched_barrier(0);  // cap quad transients
            }
        __syncthreads();   // hx(t+1) visible to all (next gemm + head)
    }

    // ---- final head (t = 15) ----
    {
        const float* wl = W_lin + ho * 256 + hq * 64;
        asm volatile("" : "+v"(wl));
        float s = 0.0f;
#pragma unroll 2
        for (int cb = 0; cb < 16; ++cb) {
            int c0 = hq * 64 + cb * 4;
            half4v u = *reinterpret_cast<const half4v*>(
                &lds_hx[ph * 256 + (c0 ^ ((ph & 7) << 4))]);
            float4 wv = *reinterpret_cast<const float4*>(wl + cb * 4);
            float h0 = (float)u[0], h1 = (float)u[1];
            float h2 = (float)u[2], h3 = (float)u[3];
            s += fmaxf(h0, 0.01f * h0) * wv.x;
            s += fmaxf(h1, 0.01f * h1) * wv.y;
            s += fmaxf(h2, 0.01f * h2) * wv.z;
            s += fmaxf(h3, 0.01f * h3) * wv.w;
        }
        s += __shfl_xor(s, 1);
        s += __shfl_xor(s, 2);
        if (hq == 0)
            out[((size_t)(row0 + ph) * 16 + 15) * 2 + ho] =
                s + (ho ? blin1 : blin0);
    }
}

// ---------------------------------------------------------------------------
extern "C" void kernel_launch(void* const* d_in, const int* in_sizes, int n_in,
                              void* d_out, int out_size, void* d_ws, size_t ws_size,
                              hipStream_t stream)
{
    const float* x    = (const float*)d_in[0];
    const float* hx   = (const float*)d_in[1];
    const float* cx   = (const float*)d_in[2];
    const float* Wih  = (const float*)d_in[3];
    const float* Whh  = (const float*)d_in[4];
    const float* bih  = (const float*)d_in[5];
    const float* bhh  = (const float*)d_in[6];
    const float* Wlin = (const float*)d_in[7];
    const float* blin = (const float*)d_in[8];
    float* out = (float*)d_out;

    half_t* wih_s = (half_t*)d_ws;             // 512 KB
    half_t* whh_s = wih_s + 1024 * 256;        // 512 KB

    shuffle_w_kernel<<<512, 64, 0, stream>>>(Wih, wih_s);
    shuffle_w_kernel<<<512, 64, 0, stream>>>(Whh, whh_s);
    lstm_kernel<<<200, 512, 0, stream>>>(x, hx, cx, bih, bhh, Wlin, blin,
                                         wih_s, whh_s, out);
}

// Round 22
// 224.423 us; speedup vs baseline: 1.2819x; 1.1106x over previous
//
#include <hip/hip_runtime.h>
#include <stdint.h>
#include <stddef.h>

// ---------- types ----------
typedef _Float16 half_t;
typedef half_t half8  __attribute__((ext_vector_type(8)));
typedef half_t half4v __attribute__((ext_vector_type(4)));
typedef float  f32x4  __attribute__((ext_vector_type(4)));

__device__ __forceinline__ float fast_sigmoid(float x) {
    float e = __builtin_amdgcn_exp2f(-1.44269504f * x);
    return __builtin_amdgcn_rcpf(1.0f + e);
}
__device__ __forceinline__ float fast_tanh(float x) {
    float e = __builtin_amdgcn_exp2f(2.88539008f * x);
    return 1.0f - 2.0f * __builtin_amdgcn_rcpf(1.0f + e);
}

// ---------------------------------------------------------------------------
// Prep: W [1024][256] f32 row-major -> wave-window-contiguous MFMA-B order.
// Tile T = g*16 + w*2 + j; slot v = g*2 + j. Element addr:
// (((w*8 + kt)*8 + v)*64 + l)*8 + e  -- window kt's 8 fragments for wave w
// are one contiguous 8 KB run (two 4 KB halves: v 0..3, v 4..7).
// Value: B[k = kt*32 + (l>>4)*8 + e, col = T*16 + (l&15)] -- same bijection
// as the LDS A-fragments (validated R1-R21, absmax 2e-3).
// ---------------------------------------------------------------------------
__global__ __launch_bounds__(64) void shuffle_w_kernel(
    const float* __restrict__ W, half_t* __restrict__ out)
{
    const int blk = blockIdx.x;         // 512 = 64 T * 8 kt
    const int T = blk >> 3, kt = blk & 7;
    const int l = threadIdx.x;
    const int w = (T & 15) >> 1, j = T & 1, g = T >> 4;
    const int v = g * 2 + j;
    const int col = T * 16 + (l & 15);
    const int k0 = kt * 32 + ((l >> 4) << 3);
    half8 vv;
#pragma unroll
    for (int e = 0; e < 8; ++e) vv[e] = (half_t)W[col * 256 + k0 + e];
    *reinterpret_cast<half8*>(
        out + ((size_t)((w * 8 + kt) * 8 + v) * 64 + l) * 8) = vv;
}

// ---------------------------------------------------------------------------
// SINGLE-PASS 4-gate GEMM with HALF-WINDOW B DOUBLE-BUFFER (R22).
// R18 dropped the b-prefetch when merging to single-pass: each window paid
// ~200 cyc exposed L2 latency before its 32 MFMAs (MfmaUtil 18.5% = ~40%
// of the gemm region stalled). Full 8-frag dbuf needs +32 regs (R13's
// failure); half-window granularity fits: prefetch the NEXT 4 b-frags,
// then 16 MFMA (~310 cyc/wave) cover the load. kt halves alternate bA/bB;
// a-frags shared across a kt's two halves. Fences per half (anti-hoist).
// In-flight: bA 16 + bB 16 + a 16 + bases ~8 (acc in AGPR).
// cowork(hw), hw = 0..15, runs in each half-window's MFMA shadow.
// ---------------------------------------------------------------------------
template <typename CoWork>
__device__ __forceinline__ void gemm_all(
    f32x4* acc, const half_t* __restrict__ lhx,
    const half_t* Ws, int w, int lm, int lg, int l, CoWork&& cowork)
{
    asm volatile("" : "+v"(Ws));   // anti-LICM: recompute bases per call
    const half_t* wb = Ws + (size_t)w * 32768 + l * 8;
    half8 bA[4], bB[4];
#pragma unroll
    for (int v = 0; v < 4; ++v)
        bA[v] = *reinterpret_cast<const half8*>(wb + v * 512);

#pragma unroll 1
    for (int kt = 0; kt < 8; ++kt) {
        const half_t* q = wb + kt * 4096;
        half8 a[4];
#pragma unroll
        for (int mt = 0; mt < 4; ++mt) {
            const int p = mt * 16 + lm;
            const int k = (kt * 32 + lg * 8) ^ ((p & 7) << 4);
            a[mt] = *reinterpret_cast<const half8*>(&lhx[p * 256 + k]);
        }
        // half 0: prefetch this kt's v=4..7 into bB; MFMA v=0..3 with bA
#pragma unroll
        for (int v = 0; v < 4; ++v)
            bB[v] = *reinterpret_cast<const half8*>(q + 2048 + v * 512);
#pragma unroll
        for (int v = 0; v < 4; ++v)
#pragma unroll
            for (int mt = 0; mt < 4; ++mt)
                acc[mt * 8 + v] = __builtin_amdgcn_mfma_f32_16x16x32_f16(
                    a[mt], bA[v], acc[mt * 8 + v], 0, 0, 0);
        cowork(kt * 2);
        __builtin_amdgcn_sched_barrier(0);
        // half 1: prefetch next kt's v=0..3 into bA; MFMA v=4..7 with bB
        const half_t* qn = wb + ((kt + 1) & 7) * 4096;
#pragma unroll
        for (int v = 0; v < 4; ++v)
            bA[v] = *reinterpret_cast<const half8*>(qn + v * 512);
#pragma unroll
        for (int v = 0; v < 4; ++v)
#pragma unroll
            for (int mt = 0; mt < 4; ++mt)
                acc[mt * 8 + 4 + v] = __builtin_amdgcn_mfma_f32_16x16x32_f16(
                    a[mt], bB[v], acc[mt * 8 + 4 + v], 0, 0, 0);
        cowork(kt * 2 + 1);
        __builtin_amdgcn_sched_barrier(0);
    }
}

// ---------------------------------------------------------------------------
// Persistent LSTM: block = 64 rows x 16 steps, 8 waves (512 threads),
// 1 blk/CU, 2 waves/SIMD. R18 base (239 us, ZERO spills; R19/R20/R21
// variants all regressed and are reverted) + R22 half-window b-dbuf.
// Ledger: cxr 32 + bA/bB 32 + a 16 + head 8 + addr ~15 = ~103 <= 128.
// LDS: hx 32 KB (XOR-swizzled) + xp 128 KB = 160 KB.
// ---------------------------------------------------------------------------
__global__ __launch_bounds__(512)
void lstm_kernel(
    const float* __restrict__ x,      // [8][256][1600]
    const float* __restrict__ hx0,    // [12800][256]
    const float* __restrict__ cx0,    // [12800][256]
    const float* __restrict__ b_ih,   // [1024]
    const float* __restrict__ b_hh,   // [1024]
    const float* __restrict__ W_lin,  // [2][256]
    const float* __restrict__ b_lin,  // [2]
    const half_t* __restrict__ Wih_s, // shuffled f16
    const half_t* __restrict__ Whh_s, // shuffled f16
    float* __restrict__ out)          // [12800][16][2]
{
    __shared__ __align__(16) half_t lds_hx[64 * 256];        // 32 KB
    __shared__ __align__(16) half_t lds_xp[8 * 32 * 64 * 4]; // 128 KB

    const int tid = threadIdx.x;
    const int w  = tid >> 6;   // wave 0..7 owns h-cols [w*32, w*32+32)
    const int l  = tid & 63;
    const int lm = l & 15;
    const int lg = l >> 4;
    const int w2 = w * 2;

    const int row0 = blockIdx.x * 64;     // 200 blocks * 64 rows
    const int bb_  = row0 / 1600;
    const int p0   = row0 % 1600;

    // ---- stage x tile into lds_hx, f16 swizzled (coalesced on p) ----
    {
        const float* xin = x + (size_t)bb_ * 409600 + p0;   // x[b][c][p0+p]
        for (int it = 0; it < 32; ++it) {
            int idx = it * 512 + tid;
            int p = idx & 63, c = idx >> 6;
            lds_hx[p * 256 + (c ^ ((p & 7) << 4))] = (half_t)xin[c * 1600 + p];
        }
    }
    __syncthreads();

    f32x4 acc[32];
    auto nocw = [](int) {};

    // ---------------- phase 0: x_proj = x @ W_ih^T + b_ih + b_hh ----------
#pragma unroll
    for (int g = 0; g < 4; ++g)
#pragma unroll
        for (int j = 0; j < 2; ++j) {
            int col = (g * 16 + w2 + j) * 16 + lm;
            float bias = b_ih[col] + b_hh[col];
#pragma unroll
            for (int mt = 0; mt < 4; ++mt)
                acc[mt * 8 + g * 2 + j] = (f32x4){bias, bias, bias, bias};
        }
    gemm_all(acc, lds_hx, Wih_s, w, lm, lg, l, nocw);

    // dump x_proj to own-wave LDS region as f16 (read back identically)
#pragma unroll
    for (int f = 0; f < 32; ++f) {
        half4v xv;
#pragma unroll
        for (int r = 0; r < 4; ++r) xv[r] = (half_t)acc[f][r];
        *reinterpret_cast<half4v*>(&lds_xp[((w * 32 + f) * 64 + l) * 4]) = xv;
    }
    __syncthreads();   // x tile fully consumed, xp written

    // ---- stage h0 into lds_hx (coalesced on c); cx into registers ----
    {
        const float* hin = hx0 + (size_t)row0 * 256;
        for (int it = 0; it < 32; ++it) {
            int idx = it * 512 + tid;
            int c = idx & 255, p = idx >> 8;
            lds_hx[p * 256 + (c ^ ((p & 7) << 4))] = (half_t)hin[p * 256 + c];
        }
    }
    float cxr[32];
#pragma unroll
    for (int mt = 0; mt < 4; ++mt)
#pragma unroll
        for (int j = 0; j < 2; ++j)
#pragma unroll
            for (int r = 0; r < 4; ++r) {
                int p = mt * 16 + lg * 4 + r;
                int c = w * 32 + j * 16 + lm;
                cxr[(mt * 2 + j) * 4 + r] = cx0[(size_t)(row0 + p) * 256 + c];
            }
    const float blin0 = b_lin[0], blin1 = b_lin[1];
    const int ph = tid >> 3;          // head: row 0..63
    const int ho = (tid >> 2) & 1;    // head: output 0..1
    const int hq = tid & 3;           // head: quarter of 256 h-cols
    __syncthreads();

    // ---------------- 16 recurrent steps ----------------
#pragma unroll 1
    for (int t = 0; t < 16; ++t) {
        // head(t-1): one cb per half-window (16 total); W_lin float4
        // pipelined one half-window ahead (8-reg state)
        const float* wl = W_lin + ho * 256 + hq * 64;
        asm volatile("" : "+v"(wl));
        float hs = 0.0f;
        float4 hwv;
        if (t > 0) hwv = *reinterpret_cast<const float4*>(wl);
        auto head_cw = [&](int wi) {
            if (t > 0) {
                int c0 = hq * 64 + wi * 4;
                half4v u = *reinterpret_cast<const half4v*>(
                    &lds_hx[ph * 256 + (c0 ^ ((ph & 7) << 4))]);
                float4 wv = hwv;
                if (wi < 15)
                    hwv = *reinterpret_cast<const float4*>(wl + (wi + 1) * 4);
                float h0 = (float)u[0], h1 = (float)u[1];
                float h2 = (float)u[2], h3 = (float)u[3];
                hs += fmaxf(h0, 0.01f * h0) * wv.x;
                hs += fmaxf(h1, 0.01f * h1) * wv.y;
                hs += fmaxf(h2, 0.01f * h2) * wv.z;
                hs += fmaxf(h3, 0.01f * h3) * wv.w;
            }
        };

        // acc init = x_proj, CHUNKED 4-frags-per-fence (R14/R18-proven)
#pragma unroll
        for (int fc = 0; fc < 32; fc += 4) {
#pragma unroll
            for (int f = fc; f < fc + 4; ++f) {
                half4v u = *reinterpret_cast<const half4v*>(
                    &lds_xp[((w * 32 + f) * 64 + l) * 4]);
#pragma unroll
                for (int r = 0; r < 4; ++r) acc[f][r] = (float)u[r];
            }
            __builtin_amdgcn_sched_barrier(0);
        }

        // single GEMM pass: all 4 gates; head(t-1) in the MFMA shadow
        gemm_all(acc, lds_hx, Whh_s, w, lm, lg, l, head_cw);
        if (t > 0) {
            hs += __shfl_xor(hs, 1);
            hs += __shfl_xor(hs, 2);
            if (hq == 0)
                out[((size_t)(row0 + ph) * 16 + (t - 1)) * 2 + ho] =
                    hs + (ho ? blin1 : blin0);
        }

        __syncthreads();   // all waves finished reading lds_hx(t)

        // epilogue: full cell update (all 4 gates local); write hx(t+1)
#pragma unroll
        for (int mt = 0; mt < 4; ++mt)
#pragma unroll
            for (int j = 0; j < 2; ++j)
#pragma unroll
                for (int r = 0; r < 4; ++r) {
                    const int ci = (mt * 2 + j) * 4 + r;
                    float iv = acc[mt * 8 + 0 + j][r];
                    float fv = acc[mt * 8 + 2 + j][r];
                    float gv = acc[mt * 8 + 4 + j][r];
                    float ov = acc[mt * 8 + 6 + j][r];
                    float cxn = fast_sigmoid(fv) * cxr[ci] +
                                fast_sigmoid(iv) * fast_tanh(gv);
                    cxr[ci] = cxn;
                    float h = fast_sigmoid(ov) * fast_tanh(cxn);
                    int p  = mt * 16 + lg * 4 + r;
                    int cc = w * 32 + j * 16 + lm;
                    lds_hx[p * 256 + (cc ^ ((p & 7) << 4))] = (half_t)h;
                }
        __syncthreads();   // hx(t+1) visible to all (next gemm + head)
    }

    // ---- final head (t = 15) ----
    {
        const float* wl = W_lin + ho * 256 + hq * 64;
        asm volatile("" : "+v"(wl));
        float s = 0.0f;
#pragma unroll 2
        for (int cb = 0; cb < 16; ++cb) {
            int c0 = hq * 64 + cb * 4;
            half4v u = *reinterpret_cast<const half4v*>(
                &lds_hx[ph * 256 + (c0 ^ ((ph & 7) << 4))]);
            float4 wv = *reinterpret_cast<const float4*>(wl + cb * 4);
            float h0 = (float)u[0], h1 = (float)u[1];
            float h2 = (float)u[2], h3 = (float)u[3];
            s += fmaxf(h0, 0.01f * h0) * wv.x;
            s += fmaxf(h1, 0.01f * h1) * wv.y;
            s += fmaxf(h2, 0.01f * h2) * wv.z;
            s += fmaxf(h3, 0.01f * h3) * wv.w;
        }
        s += __shfl_xor(s, 1);
        s += __shfl_xor(s, 2);
        if (hq == 0)
            out[((size_t)(row0 + ph) * 16 + 15) * 2 + ho] =
                s + (ho ? blin1 : blin0);
    }
}

// ---------------------------------------------------------------------------
extern "C" void kernel_launch(void* const* d_in, const int* in_sizes, int n_in,
                              void* d_out, int out_size, void* d_ws, size_t ws_size,
                              hipStream_t stream)
{
    const float* x    = (const float*)d_in[0];
    const float* hx   = (const float*)d_in[1];
    const float* cx   = (const float*)d_in[2];
    const float* Wih  = (const float*)d_in[3];
    const float* Whh  = (const float*)d_in[4];
    const float* bih  = (const float*)d_in[5];
    const float* bhh  = (const float*)d_in[6];
    const float* Wlin = (const float*)d_in[7];
    const float* blin = (const float*)d_in[8];
    float* out = (float*)d_out;

    half_t* wih_s = (half_t*)d_ws;             // 512 KB
    half_t* whh_s = wih_s + 1024 * 256;        // 512 KB

    shuffle_w_kernel<<<512, 64, 0, stream>>>(Wih, wih_s);
    shuffle_w_kernel<<<512, 64, 0, stream>>>(Whh, whh_s);
    lstm_kernel<<<200, 512, 0, stream>>>(x, hx, cx, bih, bhh, Wlin, blin,
                                         wih_s, whh_s, out);
}

// Round 23
// 223.050 us; speedup vs baseline: 1.2898x; 1.0062x over previous
//
#include <hip/hip_runtime.h>
#include <stdint.h>
#include <stddef.h>

// ---------- types ----------
typedef _Float16 half_t;
typedef half_t half8  __attribute__((ext_vector_type(8)));
typedef half_t half4v __attribute__((ext_vector_type(4)));
typedef float  f32x4  __attribute__((ext_vector_type(4)));

__device__ __forceinline__ float fast_sigmoid(float x) {
    float e = __builtin_amdgcn_exp2f(-1.44269504f * x);
    return __builtin_amdgcn_rcpf(1.0f + e);
}
__device__ __forceinline__ float fast_tanh(float x) {
    float e = __builtin_amdgcn_exp2f(2.88539008f * x);
    return 1.0f - 2.0f * __builtin_amdgcn_rcpf(1.0f + e);
}

// ---------------------------------------------------------------------------
// Prep: W [1024][256] f32 row-major -> wave-window-contiguous MFMA-B order.
// Tile T = g*16 + w*2 + j; slot v = g*2 + j. Element addr:
// (((w*8 + kt)*8 + v)*64 + l)*8 + e  -- window kt's 8 fragments for wave w
// are one contiguous 8 KB run (two 4 KB halves: v 0..3, v 4..7).
// Value: B[k = kt*32 + (l>>4)*8 + e, col = T*16 + (l&15)] -- same bijection
// as the LDS A-fragments (validated R1-R22, absmax 2e-3).
// ---------------------------------------------------------------------------
__global__ __launch_bounds__(64) void shuffle_w_kernel(
    const float* __restrict__ W, half_t* __restrict__ out)
{
    const int blk = blockIdx.x;         // 512 = 64 T * 8 kt
    const int T = blk >> 3, kt = blk & 7;
    const int l = threadIdx.x;
    const int w = (T & 15) >> 1, j = T & 1, g = T >> 4;
    const int v = g * 2 + j;
    const int col = T * 16 + (l & 15);
    const int k0 = kt * 32 + ((l >> 4) << 3);
    half8 vv;
#pragma unroll
    for (int e = 0; e < 8; ++e) vv[e] = (half_t)W[col * 256 + k0 + e];
    *reinterpret_cast<half8*>(
        out + ((size_t)((w * 8 + kt) * 8 + v) * 64 + l) * 8) = vv;
}

// ---------------------------------------------------------------------------
// SINGLE-PASS 4-gate GEMM, half-window B dbuf (R22, 224 us) + R23 A dbuf:
// a(kt+1) prefetched during half-window 1 into a ping-pong buffer aP[kt&1]
// (#pragma unroll 2 makes kt parity static per copy -- no dynamic index).
// Per half-window: 4 b prefetch + 16 MFMA + cowork + fence; half 1 also
// prefetches next kt's a. In-flight: bA/bB 32 + aP 32 + bases ~8 (acc AGPR).
// ---------------------------------------------------------------------------
template <typename CoWork>
__device__ __forceinline__ void gemm_all(
    f32x4* acc, const half_t* __restrict__ lhx,
    const half_t* Ws, int w, int lm, int lg, int l, CoWork&& cowork)
{
    asm volatile("" : "+v"(Ws));   // anti-LICM: recompute bases per call
    const half_t* wb = Ws + (size_t)w * 32768 + l * 8;
    half8 bA[4], bB[4];
    half8 aP[2][4];                // ping-pong A fragments, indexed by kt&1
#pragma unroll
    for (int v = 0; v < 4; ++v)
        bA[v] = *reinterpret_cast<const half8*>(wb + v * 512);
#pragma unroll
    for (int mt = 0; mt < 4; ++mt) {
        const int p = mt * 16 + lm;
        const int k = (lg * 8) ^ ((p & 7) << 4);
        aP[0][mt] = *reinterpret_cast<const half8*>(&lhx[p * 256 + k]);
    }

#pragma unroll 2
    for (int kt = 0; kt < 8; ++kt) {
        const half_t* q  = wb + kt * 4096;
        const half_t* qn = wb + ((kt + 1) & 7) * 4096;
        // half 0: prefetch this kt's v=4..7 into bB; MFMA v=0..3 with bA
#pragma unroll
        for (int v = 0; v < 4; ++v)
            bB[v] = *reinterpret_cast<const half8*>(q + 2048 + v * 512);
#pragma unroll
        for (int v = 0; v < 4; ++v)
#pragma unroll
            for (int mt = 0; mt < 4; ++mt)
                acc[mt * 8 + v] = __builtin_amdgcn_mfma_f32_16x16x32_f16(
                    aP[kt & 1][mt], bA[v], acc[mt * 8 + v], 0, 0, 0);
        cowork(kt * 2);
        __builtin_amdgcn_sched_barrier(0);
        // half 1: prefetch next kt's v=0..3 into bA and next kt's a into
        // aP[(kt+1)&1] (kt=7 wraps to kt=0 -- value unused, harmless);
        // MFMA v=4..7 with bB
#pragma unroll
        for (int v = 0; v < 4; ++v)
            bA[v] = *reinterpret_cast<const half8*>(qn + v * 512);
#pragma unroll
        for (int mt = 0; mt < 4; ++mt) {
            const int p = mt * 16 + lm;
            const int k = ((((kt + 1) & 7) * 32) + lg * 8) ^ ((p & 7) << 4);
            aP[(kt + 1) & 1][mt] =
                *reinterpret_cast<const half8*>(&lhx[p * 256 + k]);
        }
#pragma unroll
        for (int v = 0; v < 4; ++v)
#pragma unroll
            for (int mt = 0; mt < 4; ++mt)
                acc[mt * 8 + 4 + v] = __builtin_amdgcn_mfma_f32_16x16x32_f16(
                    aP[kt & 1][mt], bB[v], acc[mt * 8 + 4 + v], 0, 0, 0);
        cowork(kt * 2 + 1);
        __builtin_amdgcn_sched_barrier(0);
    }
}

// ---------------------------------------------------------------------------
// Persistent LSTM: block = 64 rows x 16 steps, 8 waves (512 threads),
// 1 blk/CU, 2 waves/SIMD. R22 base (224 us, zero spills) + R23:
// a-frag kt-level dbuf (above) and software-pipelined acc-init (chunk c
// issues chunk c+1's loads before its own cvts; ping-pong ib[2][4], full
// unroll keeps all acc indices static). Fences retained everywhere.
// Ledger (gemm): cxr 32 + b 32 + a 32 + head 8 + addr ~15 = ~119 <= 128.
// LDS: hx 32 KB (XOR-swizzled) + xp 128 KB = 160 KB.
// ---------------------------------------------------------------------------
__global__ __launch_bounds__(512)
void lstm_kernel(
    const float* __restrict__ x,      // [8][256][1600]
    const float* __restrict__ hx0,    // [12800][256]
    const float* __restrict__ cx0,    // [12800][256]
    const float* __restrict__ b_ih,   // [1024]
    const float* __restrict__ b_hh,   // [1024]
    const float* __restrict__ W_lin,  // [2][256]
    const float* __restrict__ b_lin,  // [2]
    const half_t* __restrict__ Wih_s, // shuffled f16
    const half_t* __restrict__ Whh_s, // shuffled f16
    float* __restrict__ out)          // [12800][16][2]
{
    __shared__ __align__(16) half_t lds_hx[64 * 256];        // 32 KB
    __shared__ __align__(16) half_t lds_xp[8 * 32 * 64 * 4]; // 128 KB

    const int tid = threadIdx.x;
    const int w  = tid >> 6;   // wave 0..7 owns h-cols [w*32, w*32+32)
    const int l  = tid & 63;
    const int lm = l & 15;
    const int lg = l >> 4;
    const int w2 = w * 2;

    const int row0 = blockIdx.x * 64;     // 200 blocks * 64 rows
    const int bb_  = row0 / 1600;
    const int p0   = row0 % 1600;

    // ---- stage x tile into lds_hx, f16 swizzled (coalesced on p) ----
    {
        const float* xin = x + (size_t)bb_ * 409600 + p0;   // x[b][c][p0+p]
        for (int it = 0; it < 32; ++it) {
            int idx = it * 512 + tid;
            int p = idx & 63, c = idx >> 6;
            lds_hx[p * 256 + (c ^ ((p & 7) << 4))] = (half_t)xin[c * 1600 + p];
        }
    }
    __syncthreads();

    f32x4 acc[32];
    auto nocw = [](int) {};

    // ---------------- phase 0: x_proj = x @ W_ih^T + b_ih + b_hh ----------
#pragma unroll
    for (int g = 0; g < 4; ++g)
#pragma unroll
        for (int j = 0; j < 2; ++j) {
            int col = (g * 16 + w2 + j) * 16 + lm;
            float bias = b_ih[col] + b_hh[col];
#pragma unroll
            for (int mt = 0; mt < 4; ++mt)
                acc[mt * 8 + g * 2 + j] = (f32x4){bias, bias, bias, bias};
        }
    gemm_all(acc, lds_hx, Wih_s, w, lm, lg, l, nocw);

    // dump x_proj to own-wave LDS region as f16 (read back identically)
#pragma unroll
    for (int f = 0; f < 32; ++f) {
        half4v xv;
#pragma unroll
        for (int r = 0; r < 4; ++r) xv[r] = (half_t)acc[f][r];
        *reinterpret_cast<half4v*>(&lds_xp[((w * 32 + f) * 64 + l) * 4]) = xv;
    }
    __syncthreads();   // x tile fully consumed, xp written

    // ---- stage h0 into lds_hx (coalesced on c); cx into registers ----
    {
        const float* hin = hx0 + (size_t)row0 * 256;
        for (int it = 0; it < 32; ++it) {
            int idx = it * 512 + tid;
            int c = idx & 255, p = idx >> 8;
            lds_hx[p * 256 + (c ^ ((p & 7) << 4))] = (half_t)hin[p * 256 + c];
        }
    }
    float cxr[32];
#pragma unroll
    for (int mt = 0; mt < 4; ++mt)
#pragma unroll
        for (int j = 0; j < 2; ++j)
#pragma unroll
            for (int r = 0; r < 4; ++r) {
                int p = mt * 16 + lg * 4 + r;
                int c = w * 32 + j * 16 + lm;
                cxr[(mt * 2 + j) * 4 + r] = cx0[(size_t)(row0 + p) * 256 + c];
            }
    const float blin0 = b_lin[0], blin1 = b_lin[1];
    const int ph = tid >> 3;          // head: row 0..63
    const int ho = (tid >> 2) & 1;    // head: output 0..1
    const int hq = tid & 3;           // head: quarter of 256 h-cols
    __syncthreads();

    // ---------------- 16 recurrent steps ----------------
#pragma unroll 1
    for (int t = 0; t < 16; ++t) {
        // head(t-1): one cb per half-window (16 total); W_lin float4
        // pipelined one half-window ahead (8-reg state)
        const float* wl = W_lin + ho * 256 + hq * 64;
        asm volatile("" : "+v"(wl));
        float hs = 0.0f;
        float4 hwv;
        if (t > 0) hwv = *reinterpret_cast<const float4*>(wl);
        auto head_cw = [&](int wi) {
            if (t > 0) {
                int c0 = hq * 64 + wi * 4;
                half4v u = *reinterpret_cast<const half4v*>(
                    &lds_hx[ph * 256 + (c0 ^ ((ph & 7) << 4))]);
                float4 wv = hwv;
                if (wi < 15)
                    hwv = *reinterpret_cast<const float4*>(wl + (wi + 1) * 4);
                float h0 = (float)u[0], h1 = (float)u[1];
                float h2 = (float)u[2], h3 = (float)u[3];
                hs += fmaxf(h0, 0.01f * h0) * wv.x;
                hs += fmaxf(h1, 0.01f * h1) * wv.y;
                hs += fmaxf(h2, 0.01f * h2) * wv.z;
                hs += fmaxf(h3, 0.01f * h3) * wv.w;
            }
        };

        // acc init = x_proj, software-pipelined chunks (loads of chunk c+1
        // issue before chunk c's cvts; full unroll -> static indices)
        {
            half4v ib[2][4];
#pragma unroll
            for (int f = 0; f < 4; ++f)
                ib[0][f] = *reinterpret_cast<const half4v*>(
                    &lds_xp[((w * 32 + f) * 64 + l) * 4]);
#pragma unroll
            for (int c = 0; c < 8; ++c) {
                if (c < 7) {
#pragma unroll
                    for (int f = 0; f < 4; ++f)
                        ib[(c + 1) & 1][f] = *reinterpret_cast<const half4v*>(
                            &lds_xp[((w * 32 + (c + 1) * 4 + f) * 64 + l) * 4]);
                }
#pragma unroll
                for (int f = 0; f < 4; ++f)
#pragma unroll
                    for (int r = 0; r < 4; ++r)
                        acc[c * 4 + f][r] = (float)ib[c & 1][f][r];
                __builtin_amdgcn_sched_barrier(0);
            }
        }

        // single GEMM pass: all 4 gates; head(t-1) in the MFMA shadow
        gemm_all(acc, lds_hx, Whh_s, w, lm, lg, l, head_cw);
        if (t > 0) {
            hs += __shfl_xor(hs, 1);
            hs += __shfl_xor(hs, 2);
            if (hq == 0)
                out[((size_t)(row0 + ph) * 16 + (t - 1)) * 2 + ho] =
                    hs + (ho ? blin1 : blin0);
        }

        __syncthreads();   // all waves finished reading lds_hx(t)

        // epilogue: full cell update (all 4 gates local); write hx(t+1)
#pragma unroll
        for (int mt = 0; mt < 4; ++mt)
#pragma unroll
            for (int j = 0; j < 2; ++j)
#pragma unroll
                for (int r = 0; r < 4; ++r) {
                    const int ci = (mt * 2 + j) * 4 + r;
                    float iv = acc[mt * 8 + 0 + j][r];
                    float fv = acc[mt * 8 + 2 + j][r];
                    float gv = acc[mt * 8 + 4 + j][r];
                    float ov = acc[mt * 8 + 6 + j][r];
                    float cxn = fast_sigmoid(fv) * cxr[ci] +
                                fast_sigmoid(iv) * fast_tanh(gv);
                    cxr[ci] = cxn;
                    float h = fast_sigmoid(ov) * fast_tanh(cxn);
                    int p  = mt * 16 + lg * 4 + r;
                    int cc = w * 32 + j * 16 + lm;
                    lds_hx[p * 256 + (cc ^ ((p & 7) << 4))] = (half_t)h;
                }
        __syncthreads();   // hx(t+1) visible to all (next gemm + head)
    }

    // ---- final head (t = 15) ----
    {
        const float* wl = W_lin + ho * 256 + hq * 64;
        asm volatile("" : "+v"(wl));
        float s = 0.0f;
#pragma unroll 2
        for (int cb = 0; cb < 16; ++cb) {
            int c0 = hq * 64 + cb * 4;
            half4v u = *reinterpret_cast<const half4v*>(
                &lds_hx[ph * 256 + (c0 ^ ((ph & 7) << 4))]);
            float4 wv = *reinterpret_cast<const float4*>(wl + cb * 4);
            float h0 = (float)u[0], h1 = (float)u[1];
            float h2 = (float)u[2], h3 = (float)u[3];
            s += fmaxf(h0, 0.01f * h0) * wv.x;
            s += fmaxf(h1, 0.01f * h1) * wv.y;
            s += fmaxf(h2, 0.01f * h2) * wv.z;
            s += fmaxf(h3, 0.01f * h3) * wv.w;
        }
        s += __shfl_xor(s, 1);
        s += __shfl_xor(s, 2);
        if (hq == 0)
            out[((size_t)(row0 + ph) * 16 + 15) * 2 + ho] =
                s + (ho ? blin1 : blin0);
    }
}

// ---------------------------------------------------------------------------
extern "C" void kernel_launch(void* const* d_in, const int* in_sizes, int n_in,
                              void* d_out, int out_size, void* d_ws, size_t ws_size,
                              hipStream_t stream)
{
    const float* x    = (const float*)d_in[0];
    const float* hx   = (const float*)d_in[1];
    const float* cx   = (const float*)d_in[2];
    const float* Wih  = (const float*)d_in[3];
    const float* Whh  = (const float*)d_in[4];
    const float* bih  = (const float*)d_in[5];
    const float* bhh  = (const float*)d_in[6];
    const float* Wlin = (const float*)d_in[7];
    const float* blin = (const float*)d_in[8];
    float* out = (float*)d_out;

    half_t* wih_s = (half_t*)d_ws;             // 512 KB
    half_t* whh_s = wih_s + 1024 * 256;        // 512 KB

    shuffle_w_kernel<<<512, 64, 0, stream>>>(Wih, wih_s);
    shuffle_w_kernel<<<512, 64, 0, stream>>>(Whh, whh_s);
    lstm_kernel<<<200, 512, 0, stream>>>(x, hx, cx, bih, bhh, Wlin, blin,
                                         wih_s, whh_s, out);
}